// Round 9
// baseline (6288.615 us; speedup 1.0000x reference)
//
#include <hip/hip_runtime.h>
#include <cstdint>

// Reference semantics (validated, absmax=0.0 — DO NOT change arithmetic):
//  - selection on RAW f32 coords, distance = fma(dz,dz, fma(dx,dx, dy*dy))
//    with dx/dy/dz plain f32 subs;
//  - min/argmax exact, FIRST-index tie-break (min global point index);
//  - output coords bf16-RNE-rounded, batch = float b.
//
// R20: active-CU VALU is issue-saturated (~396 instr-equiv/thread/iter vs
// ~240 essential). Biggest removable term: UPD's 7 scalar VALU/point.
// CDNA4 packed f32 (v_pk_add/mul/fma_f32) halves that: pair points
// (2p, 2p+1) -> 8 instr per 2 points (UPD 112 -> 64 VALU/thread/iter).
// Each packed half is an independent IEEE f32 op == scalar bits; the
// expression tree fma(dz,dz, fma(dx,dx, dy*dy)) is unchanged per element.
// Layout: s_x/s_y split arrays, stride 17 (s_x[t*17+i]) -> adjacent-slot
// pairs fuse to ds_read2_b32 (4B align ok) and the odd 68B lane stride
// covers all 32 banks (2-way alias = free). z,m are 8 named float2 each.
// Slot s of thread t is still point s*1024+t -> reduce path, tie-breaks,
// key packing, DPP wave/block reduction all unchanged from R19.
#pragma clang fp contract(off)

#define B_ 16
#define N_ 16384
#define K_ 4096
#define THREADS_ 1024
#define PTS_ (N_ / THREADS_)   // 16 points per thread (8 pairs)
#define NW_ (THREADS_ / 64)    // 16 waves per block
#define STRIDE_ 17             // padded per-thread LDS row (bank-friendly)

typedef float f2 __attribute__((ext_vector_type(2)));

#define PAIR_LIST(X) X(0) X(1) X(2) X(3) X(4) X(5) X(6) X(7)

// f32 -> bf16 RNE, returned as the bf16-representable f32 (finite inputs)
__device__ __forceinline__ float bfr(float f) {
  union { float f; uint32_t i; } c; c.f = f;
  c.i = (c.i + 0x7FFFu + ((c.i >> 16) & 1u)) & 0xFFFF0000u;
  return c.f;
}

// ---- DPP helpers (ctrl is a template constant) -----------------------------
template <int CTRL>
__device__ __forceinline__ float dpp_fmax(float v) {
  union { float f; int i; } s, p;
  s.f = v;
  p.i = __builtin_amdgcn_update_dpp(0, s.i, CTRL, 0xF, 0xF, false);
  return fmaxf(v, p.f);
}
template <int CTRL>
__device__ __forceinline__ unsigned dpp_umin(unsigned v) {
  const int p = __builtin_amdgcn_update_dpp((int)0xFFFFFFFFu, (int)v,
                                            CTRL, 0xF, 0xF, false);
  const unsigned pu = (unsigned)p;
  return pu < v ? pu : v;
}

// wave-wide (max bv, min bg among maxed) -> (wv, wg), uniform in all lanes.
__device__ __forceinline__ void wave_argmax(float bv, unsigned bg,
                                            float& wv, unsigned& wg) {
  float v = bv;
  v = dpp_fmax<0x111>(v);  // row_shr:1
  v = dpp_fmax<0x112>(v);  // row_shr:2
  v = dpp_fmax<0x114>(v);  // row_shr:4
  v = dpp_fmax<0x118>(v);  // row_shr:8
  v = dpp_fmax<0x142>(v);  // row_bcast:15
  v = dpp_fmax<0x143>(v);  // row_bcast:31
  union { float f; int i; } mx;
  mx.i = __builtin_amdgcn_readlane(__builtin_bit_cast(int, v), 63);
  unsigned c = (bv == mx.f) ? bg : 0xFFFFFFFFu;
  c = dpp_umin<0x111>(c);
  c = dpp_umin<0x112>(c);
  c = dpp_umin<0x114>(c);
  c = dpp_umin<0x118>(c);
  c = dpp_umin<0x142>(c);
  c = dpp_umin<0x143>(c);
  wg = (unsigned)__builtin_amdgcn_readlane((int)c, 63);
  wv = mx.f;
}

// u64 key max over a DPP lane-permutation (block-finalize butterfly; key is
// (f32bits(dist)<<32)|~idx so u64 max == (max dist, min index)). Exact.
template <int CTRL>
__device__ __forceinline__ unsigned long long kmax_dpp(unsigned long long k) {
  const int lo = (int)(unsigned)k;
  const int hi = (int)(unsigned)(k >> 32);
  const int plo = __builtin_amdgcn_update_dpp(lo, lo, CTRL, 0xF, 0xF, true);
  const int phi = __builtin_amdgcn_update_dpp(hi, hi, CTRL, 0xF, 0xF, true);
  const unsigned long long ok =
      ((unsigned long long)(unsigned)phi << 32) | (unsigned)plo;
  return ok > k ? ok : k;
}

__global__ __attribute__((amdgpu_flat_work_group_size(THREADS_, THREADS_),
                          amdgpu_waves_per_eu(4, 4)))
void fps_kernel(const float* __restrict__ x, float* __restrict__ out)
{
#pragma clang fp contract(off)
  const int b    = blockIdx.x;
  const int t    = threadIdx.x;
  const int lane = t & 63;
  const int wave = t >> 6;

  // x,y coords, per-thread rows of 16 slots padded to 17 (69632 B each).
  // Slot i of thread t = point i*1024+t; pair (2p,2p+1) is contiguous ->
  // ds_read2_b32; 68B lane stride covers all 32 banks (2-way = free).
  __shared__ float s_x[THREADS_ * STRIDE_];
  __shared__ float s_y[THREADS_ * STRIDE_];
  // parity-double-buffered per-wave argmax keys: one barrier per iteration
  __shared__ unsigned long long s_key[2][NW_];

  const float* xb  = x + (size_t)b * (N_ * 3);
  float* out_x     = out;                        // [B*K*3] f32 (bf16-grid values)
  float* out_batch = out + (size_t)B_ * K_ * 3;  // [B*K]   f32 cloud ids

  // batch output (buffer re-poisoned every call -> rewrite every call)
  {
    const float bb = (float)b;
    for (int i = t; i < K_; i += THREADS_) out_batch[b * K_ + i] = bb;
  }

  // z and running-min as 8 named float2 pairs (same 32-reg live set)
#define DECLP(p) f2 pz##p, pm##p;
  PAIR_LIST(DECLP)
#undef DECLP

#define LOADP(p) { const float* a_ = xb + 3 * ((2*(p)) * THREADS_ + t);      \
                   const float* b2_ = xb + 3 * ((2*(p)+1) * THREADS_ + t);   \
                   s_x[t * STRIDE_ + 2*(p)]     = a_[0];                     \
                   s_x[t * STRIDE_ + 2*(p) + 1] = b2_[0];                    \
                   s_y[t * STRIDE_ + 2*(p)]     = a_[1];                     \
                   s_y[t * STRIDE_ + 2*(p) + 1] = b2_[1];                    \
                   pz##p.x = a_[2]; pz##p.y = b2_[2];                        \
                   pm##p.x = __builtin_inff(); pm##p.y = __builtin_inff(); }
  PAIR_LIST(LOADP)
#undef LOADP

  // packed dist update (each half is an IEEE f32 op == scalar bits)
#define UPD(p) { const int a_ = t * STRIDE_ + 2*(p);                          \
                 f2 vx_; vx_.x = s_x[a_]; vx_.y = s_x[a_ + 1];                \
                 f2 vy_; vy_.x = s_y[a_]; vy_.y = s_y[a_ + 1];                \
                 const f2 dx_ = vx_ - cx2;                                    \
                 const f2 dy_ = vy_ - cy2;                                    \
                 const f2 dz_ = pz##p - cz2;                                  \
                 const f2 d_  = __builtin_elementwise_fma(dz_, dz_,           \
                                __builtin_elementwise_fma(dx_, dx_,           \
                                                          dy_ * dy_));        \
                 pm##p = __builtin_elementwise_min(pm##p, d_); }

  // max3 tree over the 16 m values; value identical to sequential max.
#define MAXTREE(M_) { const float t0_ = fmaxf(fmaxf(pm0.x, pm0.y), pm1.x);   \
                      const float t1_ = fmaxf(fmaxf(pm1.y, pm2.x), pm2.y);   \
                      const float t2_ = fmaxf(fmaxf(pm3.x, pm3.y), pm4.x);   \
                      const float t3_ = fmaxf(fmaxf(pm4.y, pm5.x), pm5.y);   \
                      const float t4_ = fmaxf(fmaxf(pm6.x, pm6.y), pm7.x);   \
                      const float u0_ = fmaxf(fmaxf(t0_, t1_), t2_);         \
                      const float u1_ = fmaxf(fmaxf(t3_, t4_), pm7.y);       \
                      M_ = fmaxf(u0_, u1_); }

  // descending equality chain: final bs = smallest slot with m==M
  // slot 2p = pm##p.x, slot 2p+1 = pm##p.y
#define IDXCHAIN(M_, BS_) { BS_ = 15;                                        \
      if (pm7.x == M_) BS_ = 14; if (pm6.y == M_) BS_ = 13;                  \
      if (pm6.x == M_) BS_ = 12; if (pm5.y == M_) BS_ = 11;                  \
      if (pm5.x == M_) BS_ = 10; if (pm4.y == M_) BS_ = 9;                   \
      if (pm4.x == M_) BS_ = 8;  if (pm3.y == M_) BS_ = 7;                   \
      if (pm3.x == M_) BS_ = 6;  if (pm2.y == M_) BS_ = 5;                   \
      if (pm2.x == M_) BS_ = 4;  if (pm1.y == M_) BS_ = 3;                   \
      if (pm1.x == M_) BS_ = 2;  if (pm0.y == M_) BS_ = 1;                   \
      if (pm0.x == M_) BS_ = 0; }

  // per-thread argmax -> wave argmax -> per-wave key in LDS
#define REDUCE_AND_POST(PARITY) {                                        \
      float bv; int bs;                                                  \
      MAXTREE(bv)                                                        \
      IDXCHAIN(bv, bs)                                                   \
      const unsigned bg = (unsigned)(bs * THREADS_ + t);                 \
      float wv; unsigned wg;                                             \
      wave_argmax(bv, bg, wv, wg);                                       \
      if (lane == 0) {                                                   \
        union { float f; unsigned u; } cv; cv.f = wv;                    \
        s_key[PARITY][wave] =                                            \
            ((unsigned long long)cv.u << 32) | (unsigned)~wg;            \
      } }

  // ---- iteration 0: seed = point 0 ----
  float cx = xb[0], cy = xb[1], cz = xb[2];
  if (t == 0) {
    const uint64_t o = ((uint64_t)b * K_) * 3;
    out_x[o + 0] = bfr(cx); out_x[o + 1] = bfr(cy); out_x[o + 2] = bfr(cz);
  }

  {
    f2 cx2; cx2.x = cx; cx2.y = cx;
    f2 cy2; cy2.x = cy; cy2.y = cy;
    f2 cz2; cz2.x = cz; cz2.y = cz;
    PAIR_LIST(UPD)                   // m = min(inf, d) = d
    REDUCE_AND_POST(0)
  }
  __syncthreads();

  // ---- iterations 1..K-1 ----
  for (int j = 1; j < K_; ++j) {
    const int rp = (j - 1) & 1;
    const int wp = j & 1;

    // finalize block argmax: 16 per-wave keys broadcast (lane&15), 4 DPP
    // levels within each 16-lane row -> every lane holds the block winner.
    unsigned long long k = s_key[rp][lane & 15];
    k = kmax_dpp<0xB1>(k);    // quad_perm lane^1
    k = kmax_dpp<0x4E>(k);    // quad_perm lane^2
    k = kmax_dpp<0x141>(k);   // row_half_mirror (lane^7, covers ^4)
    k = kmax_dpp<0x140>(k);   // row_mirror (lane^15, covers ^8)
    const unsigned idx = ~(unsigned)k;           // winner global point index
    const int gu = __builtin_amdgcn_readfirstlane((int)idx);

    // center: x,y from LDS (uniform broadcast read; slot layout aware),
    // z from global (L2; latency hides under the cz-independent xy VALU)
    const int tg = gu & (THREADS_ - 1);
    const int ig = gu >> 10;
    cx = s_x[tg * STRIDE_ + ig];
    cy = s_y[tg * STRIDE_ + ig];
    cz = xb[3 * gu + 2];
    if (t == 0) {
      const uint64_t o = ((uint64_t)b * K_ + j) * 3;
      out_x[o + 0] = bfr(cx); out_x[o + 1] = bfr(cy); out_x[o + 2] = bfr(cz);
    }

    // packed update + per-thread/wave argmax for next round
    {
      f2 cx2; cx2.x = cx; cx2.y = cx;
      f2 cy2; cy2.x = cy; cy2.y = cy;
      f2 cz2; cz2.x = cz; cz2.y = cz;
      PAIR_LIST(UPD)
      REDUCE_AND_POST(wp)
    }
    __syncthreads();
  }
#undef UPD
#undef MAXTREE
#undef IDXCHAIN
#undef REDUCE_AND_POST

}

extern "C" void kernel_launch(void* const* d_in, const int* in_sizes, int n_in,
                              void* d_out, int out_size, void* d_ws, size_t ws_size,
                              hipStream_t stream) {
  const float* x = (const float*)d_in[0];  // f32, [B*N, 3]
  float* out     = (float*)d_out;          // f32: [B*K*3] coords + [B*K] batch
  (void)in_sizes; (void)n_in; (void)out_size; (void)d_ws; (void)ws_size;
  hipLaunchKernelGGL(fps_kernel, dim3(B_), dim3(THREADS_), 0, stream, x, out);
}